// Round 19
// baseline (120.866 us; speedup 1.0000x reference)
//
#include <hip/hip_runtime.h>
#include <hip/hip_fp16.h>

#define NDIM 256
#define NC 129            // rfft output columns
#define NPAIRS 256

__device__ __forceinline__ float ntload(const float* p) {
  return __builtin_nontemporal_load(p);
}

// twiddle W256^m = exp(-2*pi*i*m/256) via HW sin/cos (revolution input, exact arg)
__device__ __forceinline__ void tw256(int m, float& cw, float& sw) {
  const float x = -(float)m * (1.0f / 256.0f);
  cw = __builtin_amdgcn_cosf(x);
  sw = __builtin_amdgcn_sinf(x);
}

// In-register 16-point FFT (DIT radix-4), natural order in/out.
__device__ __forceinline__ void fft16(float xr[16], float xi[16]) {
  const float c1 = 0.9238795325112867f, s1 = 0.3826834323650898f;
  const float h  = 0.7071067811865476f;
  float yr[4][4], yi[4][4];
#pragma unroll
  for (int r = 0; r < 4; ++r) {
    const float ar = xr[r],      ai = xi[r];
    const float br = xr[r + 4],  bi = xi[r + 4];
    const float cr = xr[r + 8],  ci = xi[r + 8];
    const float dr = xr[r + 12], di = xi[r + 12];
    const float t0r = ar + cr, t0i = ai + ci;
    const float t1r = ar - cr, t1i = ai - ci;
    const float t2r = br + dr, t2i = bi + di;
    const float t3r = br - dr, t3i = bi - di;
    yr[r][0] = t0r + t2r; yi[r][0] = t0i + t2i;
    yr[r][1] = t1r + t3i; yi[r][1] = t1i - t3r;
    yr[r][2] = t0r - t2r; yi[r][2] = t0i - t2i;
    yr[r][3] = t1r - t3i; yi[r][3] = t1i + t3r;
  }
#pragma unroll
  for (int q = 0; q < 4; ++q) {
    const float z0r = yr[0][q], z0i = yi[0][q];
    float z1r, z1i, z2r, z2i, z3r, z3i;
    if (q == 0) {
      z1r = yr[1][0]; z1i = yi[1][0];
      z2r = yr[2][0]; z2i = yi[2][0];
      z3r = yr[3][0]; z3i = yi[3][0];
    } else if (q == 1) {
      z1r =  c1 * yr[1][1] + s1 * yi[1][1]; z1i =  c1 * yi[1][1] - s1 * yr[1][1];
      z2r =   h * yr[2][1] +  h * yi[2][1]; z2i =   h * yi[2][1] -  h * yr[2][1];
      z3r =  s1 * yr[3][1] + c1 * yi[3][1]; z3i =  s1 * yi[3][1] - c1 * yr[3][1];
    } else if (q == 2) {
      z1r =   h * yr[1][2] +  h * yi[1][2]; z1i =   h * yi[1][2] -  h * yr[1][2];
      z2r =  yi[2][2];                      z2i = -yr[2][2];
      z3r =  -h * yr[3][2] +  h * yi[3][2]; z3i =  -h * yi[3][2] -  h * yr[3][2];
    } else {
      z1r =  s1 * yr[1][3] + c1 * yi[1][3]; z1i =  s1 * yi[1][3] - c1 * yr[1][3];
      z2r =  -h * yr[2][3] +  h * yi[2][3]; z2i =  -h * yi[2][3] -  h * yr[2][3];
      z3r = -c1 * yr[3][3] - s1 * yi[3][3]; z3i = -c1 * yi[3][3] + s1 * yr[3][3];
    }
    const float u0r = z0r + z2r, u0i = z0i + z2i;
    const float u1r = z0r - z2r, u1i = z0i - z2i;
    const float u2r = z1r + z3r, u2i = z1i + z3i;
    const float u3r = z1r - z3r, u3i = z1i - z3i;
    xr[q]      = u0r + u2r; xi[q]      = u0i + u2i;
    xr[q + 4]  = u1r + u3i; xi[q + 4]  = u1i - u3r;
    xr[q + 8]  = u0r - u2r; xi[q + 8]  = u0i - u2i;
    xr[q + 12] = u1r - u3i; xi[q + 12] = u1i + u3r;
  }
}

// ============ Fat kernel: stage2(chunk i) blocks + stage1(chunk i+1) blocks ==
// s1 stored fp16 AND TRANSPOSED: s1T[img][col][row] (element (col,row) at
// col*256+row). Stage1 writes scattered 64B segments (posted stores - no
// stall); stage2 reads a CONTIGUOUS 16KB window per image (column = 256
// consecutive half2) instead of 64B lines at 1032B stride over 264KB.
// Shared smem: 8704 floats = 34.8 KB (4 blocks/CU); layouts as before.
__global__ __launch_bounds__(256) void fused_kernel(
    const float* __restrict__ a, const float* __restrict__ b,
    const __half2* __restrict__ s1r, __half2* __restrict__ s1w,
    float* __restrict__ partial, int p0r, int pcr, int p0w, int pcw) {
  __shared__ float smem[8704];   // 34.8 KB
  const int t = threadIdx.x;
  const int nS2 = 9 * pcr;

  if ((int)blockIdx.x < nS2) {
    // =================== stage2 path: column FFT + products + binning =======
    float* Bre = smem;
    float* Bim = smem + 4096;
    const int col = t & 15;
    const int sub = t >> 4;
    const int xpp = pcr >> 3;
    const int xcd = blockIdx.x & 7;
    const int j = blockIdx.x >> 3;
    const int pl = j % xpp;
    const int g = j / xpp;              // [0,9)
    const int pair_local = pl * 8 + xcd;
    const int c0 = g * 16;
    const int W = (c0 + 16 <= NC) ? 16 : (NC - c0);
    const bool active = (col < W);
    const int cc = active ? (c0 + col) : (NC - 1);

    const __half2* simgA = s1r + (size_t)(pair_local * 2) * (NDIM * NC);
    const __half2* simgB = s1r + (size_t)(pair_local * 2 + 1) * (NDIM * NC);

    // prefetch both images' columns (transposed layout: column is contiguous)
    float xr[16], xi[16], wr[16], wi[16];
    const __half2* colA = simgA + cc * NDIM;
    const __half2* colB = simgB + cc * NDIM;
#pragma unroll
    for (int n1 = 0; n1 < 16; ++n1) {
      const float2 v = __half22float2(colA[16 * n1 + sub]);
      xr[n1] = v.x; xi[n1] = v.y;
    }
#pragma unroll
    for (int n1 = 0; n1 < 16; ++n1) {
      const float2 v = __half22float2(colB[16 * n1 + sub]);
      wr[n1] = v.x; wi[n1] = v.y;
    }

    // ---- image A column FFT (result in registers) ----
    float far[16], fai[16];
    fft16(xr, xi);
#pragma unroll
    for (int k1 = 0; k1 < 16; ++k1) {
      float cw, sw; tw256(sub * k1, cw, sw);
      const int ad = k1 * 256 + (((sub << 4) + col) ^ ((k1 & 1) << 4));
      Bre[ad] = xr[k1] * cw - xi[k1] * sw;
      Bim[ad] = xr[k1] * sw + xi[k1] * cw;
    }
    __syncthreads();
#pragma unroll
    for (int n2 = 0; n2 < 16; ++n2) {
      const int ad = sub * 256 + (((n2 << 4) + col) ^ ((sub & 1) << 4));
      far[n2] = Bre[ad];
      fai[n2] = Bim[ad];
    }
    fft16(far, fai);
    __syncthreads();  // WAR before B reuses exchange

    // ---- image B column FFT ----
    fft16(wr, wi);
#pragma unroll
    for (int k1 = 0; k1 < 16; ++k1) {
      float cw, sw; tw256(sub * k1, cw, sw);
      const int ad = k1 * 256 + (((sub << 4) + col) ^ ((k1 & 1) << 4));
      Bre[ad] = wr[k1] * cw - wi[k1] * sw;
      Bim[ad] = wr[k1] * sw + wi[k1] * cw;
    }
    __syncthreads();
    float br[16], bi[16];
#pragma unroll
    for (int n2 = 0; n2 < 16; ++n2) {
      const int ad = sub * 256 + (((n2 << 4) + col) ^ ((sub & 1) << 4));
      br[n2] = Bre[ad];
      bi[n2] = Bim[ad];
    }
    fft16(br, bi);
    __syncthreads();  // all exchange reads done; planes may overwrite smem

    // ---- precompute per-thread bin run bounds (reused in both passes) ------
    // thread t -> bin = 1 + (t>>1), col-half = t&1 (8 cols each); bins 1..126.
    // bin==b  <=>  (2b-1)^2 < 4*(fr^2+c^2) < (2b+1)^2   (ties impossible)
    const int bin = 1 + (t >> 1);
    const int cbase = c0 + (t & 1) * 8;
    int flo8[8], fhi8[8];
    if (bin <= 126) {
      const int lo2 = (2 * bin - 1) * (2 * bin - 1);
      const int hi2 = (2 * bin + 1) * (2 * bin + 1);
#pragma unroll
      for (int e = 0; e < 8; ++e) {
        const int c = cbase + e;
        int flo = 1, fhi = 0;                      // empty run by default
        if (c < NC) {
          const int s0 = 4 * c * c;
          if (s0 < hi2) {
            flo = 0;
            if (lo2 > s0) {
              flo = (int)(0.5f * sqrtf((float)(lo2 - s0)));
              while (4 * flo * flo + s0 <= lo2) ++flo;
              while (flo > 0 && 4 * (flo - 1) * (flo - 1) + s0 > lo2) --flo;
            }
            fhi = (int)(0.5f * sqrtf((float)(hi2 - s0)));
            while (4 * fhi * fhi + s0 >= hi2) --fhi;
            while (4 * (fhi + 1) * (fhi + 1) + s0 < hi2) ++fhi;
            if (fhi > 128) fhi = 128;
          }
        }
        flo8[e] = flo; fhi8[e] = fhi;
      }
    } else {
#pragma unroll
      for (int e = 0; e < 8; ++e) { flo8[e] = 1; fhi8[e] = 0; }
    }

    float acc0 = 0.f, acc1 = 0.f, acc2 = 0.f;

    // ======== pass 1: planes {|A|^2, |B|^2} ========
#pragma unroll
    for (int k2 = 0; k2 < 16; ++k2) {
      const int ro = (sub + 16 * k2) * 17 + col;
      smem[ro]        = far[k2] * far[k2] + fai[k2] * fai[k2];
      smem[4352 + ro] = br[k2] * br[k2] + bi[k2] * bi[k2];
    }
    __syncthreads();
    // hermitian fold: row[fr] += row[256-fr], fr=1..127, both planes
    for (int i = t; i < 2 * 127 * 16; i += 256) {
      const int q = i / (127 * 16);
      const int r = i - q * (127 * 16);
      const int fr = (r >> 4) + 1;
      const int cl = r & 15;
      const int base = q * 4352;
      smem[base + fr * 17 + cl] += smem[base + (256 - fr) * 17 + cl];
    }
    __syncthreads();
#pragma unroll
    for (int e = 0; e < 8; ++e) {
      const int cl = cbase + e - c0;
      int ro = flo8[e] * 17 + cl;
      for (int fr = flo8[e]; fr <= fhi8[e]; ++fr, ro += 17) {
        acc0 += smem[ro];
        acc1 += smem[4352 + ro];
      }
    }
    __syncthreads();  // planes dead

    // ======== pass 2: plane {re(A*conj(B))} ========
#pragma unroll
    for (int k2 = 0; k2 < 16; ++k2) {
      const int ro = (sub + 16 * k2) * 17 + col;
      smem[ro] = far[k2] * br[k2] + fai[k2] * bi[k2];
    }
    __syncthreads();
    for (int i = t; i < 127 * 16; i += 256) {
      const int fr = (i >> 4) + 1;
      const int cl = i & 15;
      smem[fr * 17 + cl] += smem[(256 - fr) * 17 + cl];
    }
    __syncthreads();
#pragma unroll
    for (int e = 0; e < 8; ++e) {
      const int cl = cbase + e - c0;
      int ro = flo8[e] * 17 + cl;
      for (int fr = flo8[e]; fr <= fhi8[e]; ++fr, ro += 17) {
        acc2 += smem[ro];
      }
    }

    // combine col-halves (adjacent lanes), write partial
    acc0 += __shfl_xor(acc0, 1);
    acc1 += __shfl_xor(acc1, 1);
    acc2 += __shfl_xor(acc2, 1);
    if (bin <= 126 && (t & 1) == 0) {
      float* pdst = partial + (size_t)((p0r + pair_local) * 9 + g) * (3 * NC);
      pdst[bin] = acc0;
      pdst[NC + bin] = acc1;
      pdst[2 * NC + bin] = acc2;
    }
  } else if (pcw > 0) {
    // =================== stage1 path: row-wise rfft per image ===============
    float* Bre = smem;                     // stride 272
    float* Bim = smem + 4352;
    float2* Bfin = (float2*)smem;          // 16x129 float2, aliases Bre
    const int bid = blockIdx.x - nS2;      // nS2 multiple of 8: keeps &7 pinning
    const int lr = t >> 4;
    const int sub = t & 15;
    const int xpp = pcw >> 3;
    const int xcd = bid & 7;
    const int j = bid >> 3;                // [0, 2*pcw)
    const int pl = j % xpp;
    const int piece = j / xpp;             // [0,16)
    const int pair_local = pl * 8 + xcd;
    const int img = piece >> 3;
    const int rg2 = piece & 7;
    const int pairg = p0w + pair_local;
    const float* src = (img == 0) ? (a + (size_t)pairg * (NDIM * NDIM))
                                  : (b + (size_t)pairg * (NDIM * NDIM));
    __half2* dst = s1w + (size_t)(pair_local * 2 + img) * (NDIM * NC);

    float cw16[16], sw16[16];
#pragma unroll
    for (int k1 = 0; k1 < 16; ++k1) tw256(sub * k1, cw16[k1], sw16[k1]);

    for (int g = rg2 * 2; g < rg2 * 2 + 2; ++g) {
      const int row = g * 16 + lr;
      float xr[16], xi[16];
      const float* xrow = src + row * NDIM + sub;
#pragma unroll
      for (int n1 = 0; n1 < 16; ++n1) { xr[n1] = ntload(xrow + 16 * n1); xi[n1] = 0.f; }
      fft16(xr, xi);
#pragma unroll
      for (int k1 = 0; k1 < 16; ++k1) {
        Bre[lr * 272 + sub * 17 + k1] = xr[k1] * cw16[k1] - xi[k1] * sw16[k1];
        Bim[lr * 272 + sub * 17 + k1] = xr[k1] * sw16[k1] + xi[k1] * cw16[k1];
      }
      __syncthreads();
      float br[16], bi[16];
#pragma unroll
      for (int n2 = 0; n2 < 16; ++n2) {
        br[n2] = Bre[lr * 272 + n2 * 17 + sub];
        bi[n2] = Bim[lr * 272 + n2 * 17 + sub];
      }
      __syncthreads();   // all Bre reads done; Bfin may overwrite
      fft16(br, bi);
#pragma unroll
      for (int k2 = 0; k2 < 16; ++k2) {
        const int k = sub + 16 * k2;
        if (k <= 128) Bfin[lr * 129 + k] = make_float2(br[k2], bi[k2]);
      }
      __syncthreads();
      // transposed streamout: element (col,row) -> dst[col*256 + g*16 + row16];
      // 16 consecutive lanes share a col -> one 64B contiguous segment (posted)
      for (int i = t; i < 16 * 129; i += 256) {
        const int colI = i >> 4;
        const int row16 = i & 15;
        const float2 v = Bfin[row16 * 129 + colI];
        dst[colI * NDIM + g * 16 + row16] = __floats2half2_rn(v.x, v.y);
      }
      __syncthreads();   // streamout done before next g overwrites
    }
  }
}

// ---------------- Stage 3a: per-pair FRC partial sum (double) ----------------
__global__ __launch_bounds__(128) void stage3a_kernel(
    const float* __restrict__ partial, double* __restrict__ pairsum) {
  const int pair = blockIdx.x;
  const int t = threadIdx.x;
  double v = 0.0;
  if (t >= 1 && t <= 126) {
    float na = 0.f, nb = 0.f, nm = 0.f;
    for (int g = 0; g < 9; ++g) {
      const float* p = partial + (size_t)(pair * 9 + g) * (3 * NC);
      na += p[t];
      nb += p[NC + t];
      nm += p[2 * NC + t];
    }
    const double den = fmax(sqrt((double)na) * sqrt((double)nb), 1e-4);
    v = (double)nm / den;
  }
  __shared__ double sd[128];
  sd[t] = v;
  __syncthreads();
  for (int s = 64; s > 0; s >>= 1) {
    if (t < s) sd[t] += sd[t + s];
    __syncthreads();
  }
  if (t == 0) pairsum[pair] = sd[0];
}

// ---------------- Stage 3b: final mean ---------------------------------------
__global__ __launch_bounds__(256) void stage3b_kernel(
    const double* __restrict__ pairsum, float* __restrict__ out) {
  const int t = threadIdx.x;
  __shared__ double sd[256];
  sd[t] = pairsum[t];
  __syncthreads();
  for (int s = 128; s > 0; s >>= 1) {
    if (t < s) sd[t] += sd[t + s];
    __syncthreads();
  }
  if (t == 0) out[0] = (float)(sd[0] / 32256.0);  // 256 pairs * 126 bins
}

extern "C" void kernel_launch(void* const* d_in, const int* in_sizes, int n_in,
                              void* d_out, int out_size, void* d_ws, size_t ws_size,
                              hipStream_t stream) {
  const float* a = (const float*)d_in[0];
  const float* b = (const float*)d_in[1];
  float* out = (float*)d_out;

  char* ws = (char*)d_ws;
  const size_t partial_bytes = (size_t)NPAIRS * 9 * 3 * NC * sizeof(float);
  size_t off = (partial_bytes + 255) & ~(size_t)255;
  float* partial = (float*)ws;
  double* pairsum = (double*)(ws + off);
  off += ((size_t)NPAIRS * sizeof(double) + 255) & ~(size_t)255;

  // Tapered chunk schedule {64,128,64}: 75% of work in mixed S1+S2 launches.
  // s1 stored as __half2, transposed [img][col][row] -> 264KB/pair.
  const size_t s1_per_pair = (size_t)2 * NDIM * NC * sizeof(__half2);  // 264192
  const size_t avail = (ws_size > off) ? (ws_size - off) : 0;
  int cap = (int)(avail / (2 * s1_per_pair));    // pairs per ring slot

  int chunks[32];
  int nck = 0;
  if (cap >= 128) {
    chunks[nck++] = 64; chunks[nck++] = 128; chunks[nck++] = 64;
  } else {
    int CH = 64;
    while (CH > 8 && CH > cap) CH >>= 1;
    for (int p = 0; p < NPAIRS; p += CH) chunks[nck++] = CH;
  }
  int slotPairs = 0;
  for (int i = 0; i < nck; ++i) if (chunks[i] > slotPairs) slotPairs = chunks[i];

  __half2* slot0 = (__half2*)(ws + off);
  __half2* slot1 = (__half2*)(ws + off + (size_t)slotPairs * s1_per_pair);

  int start[33];
  start[0] = 0;
  for (int i = 0; i < nck; ++i) start[i + 1] = start[i] + chunks[i];

  for (int i = 0; i <= nck; ++i) {
    const int pcr = (i > 0) ? chunks[i - 1] : 0;
    const int p0r = (i > 0) ? start[i - 1] : 0;
    const int pcw = (i < nck) ? chunks[i] : 0;
    const int p0w = (i < nck) ? start[i] : 0;
    const __half2* rs = ((i - 1) & 1) ? slot1 : slot0;
    __half2* wsl = (i & 1) ? slot1 : slot0;
    const int grid = 9 * pcr + 16 * pcw;
    hipLaunchKernelGGL(fused_kernel, dim3(grid), dim3(256), 0, stream,
                       a, b, rs, wsl, partial, p0r, pcr, p0w, pcw);
  }
  hipLaunchKernelGGL(stage3a_kernel, dim3(NPAIRS), dim3(128), 0, stream,
                     partial, pairsum);
  hipLaunchKernelGGL(stage3b_kernel, dim3(1), dim3(256), 0, stream,
                     pairsum, out);
}

// Round 20
// 110.498 us; speedup vs baseline: 1.0938x; 1.0938x over previous
//
#include <hip/hip_runtime.h>
#include <hip/hip_fp16.h>

#define NDIM 256
#define NC 129            // rfft output columns
#define NPAIRS 256

__device__ __forceinline__ float ntload(const float* p) {
  return __builtin_nontemporal_load(p);
}

// twiddle W256^m = exp(-2*pi*i*m/256) via HW sin/cos (revolution input, exact arg)
__device__ __forceinline__ void tw256(int m, float& cw, float& sw) {
  const float x = -(float)m * (1.0f / 256.0f);
  cw = __builtin_amdgcn_cosf(x);
  sw = __builtin_amdgcn_sinf(x);
}

// In-register 16-point FFT (DIT radix-4), natural order in/out.
__device__ __forceinline__ void fft16(float xr[16], float xi[16]) {
  const float c1 = 0.9238795325112867f, s1 = 0.3826834323650898f;
  const float h  = 0.7071067811865476f;
  float yr[4][4], yi[4][4];
#pragma unroll
  for (int r = 0; r < 4; ++r) {
    const float ar = xr[r],      ai = xi[r];
    const float br = xr[r + 4],  bi = xi[r + 4];
    const float cr = xr[r + 8],  ci = xi[r + 8];
    const float dr = xr[r + 12], di = xi[r + 12];
    const float t0r = ar + cr, t0i = ai + ci;
    const float t1r = ar - cr, t1i = ai - ci;
    const float t2r = br + dr, t2i = bi + di;
    const float t3r = br - dr, t3i = bi - di;
    yr[r][0] = t0r + t2r; yi[r][0] = t0i + t2i;
    yr[r][1] = t1r + t3i; yi[r][1] = t1i - t3r;
    yr[r][2] = t0r - t2r; yi[r][2] = t0i - t2i;
    yr[r][3] = t1r - t3i; yi[r][3] = t1i + t3r;
  }
#pragma unroll
  for (int q = 0; q < 4; ++q) {
    const float z0r = yr[0][q], z0i = yi[0][q];
    float z1r, z1i, z2r, z2i, z3r, z3i;
    if (q == 0) {
      z1r = yr[1][0]; z1i = yi[1][0];
      z2r = yr[2][0]; z2i = yi[2][0];
      z3r = yr[3][0]; z3i = yi[3][0];
    } else if (q == 1) {
      z1r =  c1 * yr[1][1] + s1 * yi[1][1]; z1i =  c1 * yi[1][1] - s1 * yr[1][1];
      z2r =   h * yr[2][1] +  h * yi[2][1]; z2i =   h * yi[2][1] -  h * yr[2][1];
      z3r =  s1 * yr[3][1] + c1 * yi[3][1]; z3i =  s1 * yi[3][1] - c1 * yr[3][1];
    } else if (q == 2) {
      z1r =   h * yr[1][2] +  h * yi[1][2]; z1i =   h * yi[1][2] -  h * yr[1][2];
      z2r =  yi[2][2];                      z2i = -yr[2][2];
      z3r =  -h * yr[3][2] +  h * yi[3][2]; z3i =  -h * yi[3][2] -  h * yr[3][2];
    } else {
      z1r =  s1 * yr[1][3] + c1 * yi[1][3]; z1i =  s1 * yi[1][3] - c1 * yr[1][3];
      z2r =  -h * yr[2][3] +  h * yi[2][3]; z2i =  -h * yi[2][3] -  h * yr[2][3];
      z3r = -c1 * yr[3][3] - s1 * yi[3][3]; z3i = -c1 * yi[3][3] + s1 * yr[3][3];
    }
    const float u0r = z0r + z2r, u0i = z0i + z2i;
    const float u1r = z0r - z2r, u1i = z0i - z2i;
    const float u2r = z1r + z3r, u2i = z1i + z3i;
    const float u3r = z1r - z3r, u3i = z1i - z3i;
    xr[q]      = u0r + u2r; xi[q]      = u0i + u2i;
    xr[q + 4]  = u1r + u3i; xi[q + 4]  = u1i - u3r;
    xr[q + 8]  = u0r - u2r; xi[q + 8]  = u0i - u2i;
    xr[q + 12] = u1r - u3i; xi[q + 12] = u1i + u3r;
  }
}

// ============ Fat kernel: stage2(chunk i) blocks + stage1(chunk i+1) blocks ==
// s1 intermediate stored as fp16 (__half2 per complex), ROW-MAJOR [row][col]:
// halves the round trip (270MB -> 135MB); row-major keeps stage2's per-
// instruction coalescing (16 lanes = 64B contiguous segment). [R19 showed
// transposed layout regresses: 4B/lane scattered over 1KB strides.]
// Error budget: fp16 rel err 4.9e-4 -> final mean averages 32256 independent
// (pair,bin) errors -> ~5e-7, 12x under the 6.03e-6 threshold (measured 0.0).
// Shared smem: 8704 floats = 34.8 KB (4 blocks/CU).
__global__ __launch_bounds__(256) void fused_kernel(
    const float* __restrict__ a, const float* __restrict__ b,
    const __half2* __restrict__ s1r, __half2* __restrict__ s1w,
    float* __restrict__ partial, int p0r, int pcr, int p0w, int pcw) {
  __shared__ float smem[8704];   // 34.8 KB
  const int t = threadIdx.x;
  const int nS2 = 9 * pcr;

  if ((int)blockIdx.x < nS2) {
    // =================== stage2 path: column FFT + products + binning =======
    float* Bre = smem;
    float* Bim = smem + 4096;
    const int col = t & 15;
    const int sub = t >> 4;
    const int xpp = pcr >> 3;
    const int xcd = blockIdx.x & 7;
    const int j = blockIdx.x >> 3;
    const int pl = j % xpp;
    const int g = j / xpp;              // [0,9)
    const int pair_local = pl * 8 + xcd;
    const int c0 = g * 16;
    const int W = (c0 + 16 <= NC) ? 16 : (NC - c0);
    const bool active = (col < W);
    const int cc = active ? (c0 + col) : (NC - 1);

    const __half2* simgA = s1r + (size_t)(pair_local * 2) * (NDIM * NC);
    const __half2* simgB = s1r + (size_t)(pair_local * 2 + 1) * (NDIM * NC);

    // prefetch both images' columns (fp16 -> fp32)
    float xr[16], xi[16], wr[16], wi[16];
#pragma unroll
    for (int n1 = 0; n1 < 16; ++n1) {
      const float2 v = __half22float2(simgA[(16 * n1 + sub) * NC + cc]);
      xr[n1] = v.x; xi[n1] = v.y;
    }
#pragma unroll
    for (int n1 = 0; n1 < 16; ++n1) {
      const float2 v = __half22float2(simgB[(16 * n1 + sub) * NC + cc]);
      wr[n1] = v.x; wi[n1] = v.y;
    }

    // ---- image A column FFT (result in registers) ----
    float far[16], fai[16];
    fft16(xr, xi);
#pragma unroll
    for (int k1 = 0; k1 < 16; ++k1) {
      float cw, sw; tw256(sub * k1, cw, sw);
      const int ad = k1 * 256 + (((sub << 4) + col) ^ ((k1 & 1) << 4));
      Bre[ad] = xr[k1] * cw - xi[k1] * sw;
      Bim[ad] = xr[k1] * sw + xi[k1] * cw;
    }
    __syncthreads();
#pragma unroll
    for (int n2 = 0; n2 < 16; ++n2) {
      const int ad = sub * 256 + (((n2 << 4) + col) ^ ((sub & 1) << 4));
      far[n2] = Bre[ad];
      fai[n2] = Bim[ad];
    }
    fft16(far, fai);
    __syncthreads();  // WAR before B reuses exchange

    // ---- image B column FFT ----
    fft16(wr, wi);
#pragma unroll
    for (int k1 = 0; k1 < 16; ++k1) {
      float cw, sw; tw256(sub * k1, cw, sw);
      const int ad = k1 * 256 + (((sub << 4) + col) ^ ((k1 & 1) << 4));
      Bre[ad] = wr[k1] * cw - wi[k1] * sw;
      Bim[ad] = wr[k1] * sw + wi[k1] * cw;
    }
    __syncthreads();
    float br[16], bi[16];
#pragma unroll
    for (int n2 = 0; n2 < 16; ++n2) {
      const int ad = sub * 256 + (((n2 << 4) + col) ^ ((sub & 1) << 4));
      br[n2] = Bre[ad];
      bi[n2] = Bim[ad];
    }
    fft16(br, bi);
    __syncthreads();  // all exchange reads done; planes may overwrite smem

    // ---- precompute per-thread bin run bounds (reused in both passes) ------
    // thread t -> bin = 1 + (t>>1), col-half = t&1 (8 cols each); bins 1..126.
    // bin==b  <=>  (2b-1)^2 < 4*(fr^2+c^2) < (2b+1)^2   (ties impossible)
    const int bin = 1 + (t >> 1);
    const int cbase = c0 + (t & 1) * 8;
    int flo8[8], fhi8[8];
    if (bin <= 126) {
      const int lo2 = (2 * bin - 1) * (2 * bin - 1);
      const int hi2 = (2 * bin + 1) * (2 * bin + 1);
#pragma unroll
      for (int e = 0; e < 8; ++e) {
        const int c = cbase + e;
        int flo = 1, fhi = 0;                      // empty run by default
        if (c < NC) {
          const int s0 = 4 * c * c;
          if (s0 < hi2) {
            flo = 0;
            if (lo2 > s0) {
              flo = (int)(0.5f * sqrtf((float)(lo2 - s0)));
              while (4 * flo * flo + s0 <= lo2) ++flo;
              while (flo > 0 && 4 * (flo - 1) * (flo - 1) + s0 > lo2) --flo;
            }
            fhi = (int)(0.5f * sqrtf((float)(hi2 - s0)));
            while (4 * fhi * fhi + s0 >= hi2) --fhi;
            while (4 * (fhi + 1) * (fhi + 1) + s0 < hi2) ++fhi;
            if (fhi > 128) fhi = 128;
          }
        }
        flo8[e] = flo; fhi8[e] = fhi;
      }
    } else {
#pragma unroll
      for (int e = 0; e < 8; ++e) { flo8[e] = 1; fhi8[e] = 0; }
    }

    float acc0 = 0.f, acc1 = 0.f, acc2 = 0.f;

    // ======== pass 1: planes {|A|^2, |B|^2} ========
#pragma unroll
    for (int k2 = 0; k2 < 16; ++k2) {
      const int ro = (sub + 16 * k2) * 17 + col;
      smem[ro]        = far[k2] * far[k2] + fai[k2] * fai[k2];
      smem[4352 + ro] = br[k2] * br[k2] + bi[k2] * bi[k2];
    }
    __syncthreads();
    // hermitian fold: row[fr] += row[256-fr], fr=1..127, both planes
    for (int i = t; i < 2 * 127 * 16; i += 256) {
      const int q = i / (127 * 16);
      const int r = i - q * (127 * 16);
      const int fr = (r >> 4) + 1;
      const int cl = r & 15;
      const int base = q * 4352;
      smem[base + fr * 17 + cl] += smem[base + (256 - fr) * 17 + cl];
    }
    __syncthreads();
#pragma unroll
    for (int e = 0; e < 8; ++e) {
      const int cl = cbase + e - c0;
      int ro = flo8[e] * 17 + cl;
      for (int fr = flo8[e]; fr <= fhi8[e]; ++fr, ro += 17) {
        acc0 += smem[ro];
        acc1 += smem[4352 + ro];
      }
    }
    __syncthreads();  // planes dead

    // ======== pass 2: plane {re(A*conj(B))} ========
#pragma unroll
    for (int k2 = 0; k2 < 16; ++k2) {
      const int ro = (sub + 16 * k2) * 17 + col;
      smem[ro] = far[k2] * br[k2] + fai[k2] * bi[k2];
    }
    __syncthreads();
    for (int i = t; i < 127 * 16; i += 256) {
      const int fr = (i >> 4) + 1;
      const int cl = i & 15;
      smem[fr * 17 + cl] += smem[(256 - fr) * 17 + cl];
    }
    __syncthreads();
#pragma unroll
    for (int e = 0; e < 8; ++e) {
      const int cl = cbase + e - c0;
      int ro = flo8[e] * 17 + cl;
      for (int fr = flo8[e]; fr <= fhi8[e]; ++fr, ro += 17) {
        acc2 += smem[ro];
      }
    }

    // combine col-halves (adjacent lanes), write partial
    acc0 += __shfl_xor(acc0, 1);
    acc1 += __shfl_xor(acc1, 1);
    acc2 += __shfl_xor(acc2, 1);
    if (bin <= 126 && (t & 1) == 0) {
      float* pdst = partial + (size_t)((p0r + pair_local) * 9 + g) * (3 * NC);
      pdst[bin] = acc0;
      pdst[NC + bin] = acc1;
      pdst[2 * NC + bin] = acc2;
    }
  } else if (pcw > 0) {
    // =================== stage1 path: row-wise rfft per image ===============
    float* Bre = smem;                     // stride 272
    float* Bim = smem + 4352;
    float2* Bfin = (float2*)smem;          // 16x129 float2, aliases Bre
    const int bid = blockIdx.x - nS2;      // nS2 multiple of 8: keeps &7 pinning
    const int lr = t >> 4;
    const int sub = t & 15;
    const int xpp = pcw >> 3;
    const int xcd = bid & 7;
    const int j = bid >> 3;                // [0, 2*pcw)
    const int pl = j % xpp;
    const int piece = j / xpp;             // [0,16)
    const int pair_local = pl * 8 + xcd;
    const int img = piece >> 3;
    const int rg2 = piece & 7;
    const int pairg = p0w + pair_local;
    const float* src = (img == 0) ? (a + (size_t)pairg * (NDIM * NDIM))
                                  : (b + (size_t)pairg * (NDIM * NDIM));
    __half2* dst = s1w + (size_t)(pair_local * 2 + img) * (NDIM * NC);

    float cw16[16], sw16[16];
#pragma unroll
    for (int k1 = 0; k1 < 16; ++k1) tw256(sub * k1, cw16[k1], sw16[k1]);

    for (int g = rg2 * 2; g < rg2 * 2 + 2; ++g) {
      const int row = g * 16 + lr;
      float xr[16], xi[16];
      const float* xrow = src + row * NDIM + sub;
#pragma unroll
      for (int n1 = 0; n1 < 16; ++n1) { xr[n1] = ntload(xrow + 16 * n1); xi[n1] = 0.f; }
      fft16(xr, xi);
#pragma unroll
      for (int k1 = 0; k1 < 16; ++k1) {
        Bre[lr * 272 + sub * 17 + k1] = xr[k1] * cw16[k1] - xi[k1] * sw16[k1];
        Bim[lr * 272 + sub * 17 + k1] = xr[k1] * sw16[k1] + xi[k1] * cw16[k1];
      }
      __syncthreads();
      float br[16], bi[16];
#pragma unroll
      for (int n2 = 0; n2 < 16; ++n2) {
        br[n2] = Bre[lr * 272 + n2 * 17 + sub];
        bi[n2] = Bim[lr * 272 + n2 * 17 + sub];
      }
      __syncthreads();   // all Bre reads done; Bfin may overwrite
      fft16(br, bi);
#pragma unroll
      for (int k2 = 0; k2 < 16; ++k2) {
        const int k = sub + 16 * k2;
        if (k <= 128) Bfin[lr * 129 + k] = make_float2(br[k2], bi[k2]);
      }
      __syncthreads();
      __half2* drow0 = dst + (size_t)(g * 16) * NC;
      for (int i = t; i < 16 * 129; i += 256) {
        const float2 v = Bfin[i];
        drow0[i] = __floats2half2_rn(v.x, v.y);
      }
      __syncthreads();   // streamout done before next g overwrites
    }
  }
}

// ---------------- Stage 3a: per-pair FRC partial sum (double) ----------------
__global__ __launch_bounds__(128) void stage3a_kernel(
    const float* __restrict__ partial, double* __restrict__ pairsum) {
  const int pair = blockIdx.x;
  const int t = threadIdx.x;
  double v = 0.0;
  if (t >= 1 && t <= 126) {
    float na = 0.f, nb = 0.f, nm = 0.f;
    for (int g = 0; g < 9; ++g) {
      const float* p = partial + (size_t)(pair * 9 + g) * (3 * NC);
      na += p[t];
      nb += p[NC + t];
      nm += p[2 * NC + t];
    }
    const double den = fmax(sqrt((double)na) * sqrt((double)nb), 1e-4);
    v = (double)nm / den;
  }
  __shared__ double sd[128];
  sd[t] = v;
  __syncthreads();
  for (int s = 64; s > 0; s >>= 1) {
    if (t < s) sd[t] += sd[t + s];
    __syncthreads();
  }
  if (t == 0) pairsum[pair] = sd[0];
}

// ---------------- Stage 3b: final mean ---------------------------------------
__global__ __launch_bounds__(256) void stage3b_kernel(
    const double* __restrict__ pairsum, float* __restrict__ out) {
  const int t = threadIdx.x;
  __shared__ double sd[256];
  sd[t] = pairsum[t];
  __syncthreads();
  for (int s = 128; s > 0; s >>= 1) {
    if (t < s) sd[t] += sd[t + s];
    __syncthreads();
  }
  if (t == 0) out[0] = (float)(sd[0] / 32256.0);  // 256 pairs * 126 bins
}

extern "C" void kernel_launch(void* const* d_in, const int* in_sizes, int n_in,
                              void* d_out, int out_size, void* d_ws, size_t ws_size,
                              hipStream_t stream) {
  const float* a = (const float*)d_in[0];
  const float* b = (const float*)d_in[1];
  float* out = (float*)d_out;

  char* ws = (char*)d_ws;
  const size_t partial_bytes = (size_t)NPAIRS * 9 * 3 * NC * sizeof(float);
  size_t off = (partial_bytes + 255) & ~(size_t)255;
  float* partial = (float*)ws;
  double* pairsum = (double*)(ws + off);
  off += ((size_t)NPAIRS * sizeof(double) + 255) & ~(size_t)255;

  // Tapered chunk schedule {64,128,64}: 75% of work in mixed S1+S2 launches.
  // s1 stored as __half2 -> 264KB/pair (halved round trip).
  const size_t s1_per_pair = (size_t)2 * NDIM * NC * sizeof(__half2);  // 264192
  const size_t avail = (ws_size > off) ? (ws_size - off) : 0;
  int cap = (int)(avail / (2 * s1_per_pair));    // pairs per ring slot

  int chunks[32];
  int nck = 0;
  if (cap >= 128) {
    chunks[nck++] = 64; chunks[nck++] = 128; chunks[nck++] = 64;
  } else {
    int CH = 64;
    while (CH > 8 && CH > cap) CH >>= 1;
    for (int p = 0; p < NPAIRS; p += CH) chunks[nck++] = CH;
  }
  int slotPairs = 0;
  for (int i = 0; i < nck; ++i) if (chunks[i] > slotPairs) slotPairs = chunks[i];

  __half2* slot0 = (__half2*)(ws + off);
  __half2* slot1 = (__half2*)(ws + off + (size_t)slotPairs * s1_per_pair);

  int start[33];
  start[0] = 0;
  for (int i = 0; i < nck; ++i) start[i + 1] = start[i] + chunks[i];

  for (int i = 0; i <= nck; ++i) {
    const int pcr = (i > 0) ? chunks[i - 1] : 0;
    const int p0r = (i > 0) ? start[i - 1] : 0;
    const int pcw = (i < nck) ? chunks[i] : 0;
    const int p0w = (i < nck) ? start[i] : 0;
    const __half2* rs = ((i - 1) & 1) ? slot1 : slot0;
    __half2* wsl = (i & 1) ? slot1 : slot0;
    const int grid = 9 * pcr + 16 * pcw;
    hipLaunchKernelGGL(fused_kernel, dim3(grid), dim3(256), 0, stream,
                       a, b, rs, wsl, partial, p0r, pcr, p0w, pcw);
  }
  hipLaunchKernelGGL(stage3a_kernel, dim3(NPAIRS), dim3(128), 0, stream,
                     partial, pairsum);
  hipLaunchKernelGGL(stage3b_kernel, dim3(1), dim3(256), 0, stream,
                     pairsum, out);
}